// Round 4
// baseline (308.973 us; speedup 1.0000x reference)
//
#include <hip/hip_runtime.h>
#include <hip/hip_bf16.h>
#include <cstdint>

// SelfAttention: B=8, S=2048, D_IN=D_OUT=768, fp32 in/out.
// R12 = R11 (split-half 8-phase 256x256 GEMM) with m201-faithful FENCE
// DISCIPLINE. R10/R11 post-mortem: both landed at the 2-phase plateau
// (83us/GEMM, MfmaUtil 27%) because every in-loop barrier/wait was an
// asm with ::: "memory" — the AMDGPU backend treats mayLoad/mayStore asm
// conservatively and inserts s_waitcnt vmcnt(0) before it, force-draining
// the staged global_load_lds every tile (T4 counted-vmcnt nullified).
// R12: raw __builtin_amdgcn_s_barrier(), clobber-FREE s_waitcnt asm, and
// __builtin_amdgcn_sched_barrier(0) at every phase boundary (rule #18):
// after reads+stages (pins reads above the barrier), after each lgkmcnt(0)
// (pins MFMA below the wait), after MFMA clusters, and between P4 stages
// and the counted vmcnt (keeps the retire ledger exact).
// Schedule (unchanged from R11): wave wr owns rows wr*64 within EACH half;
// wc owns cols wc*32 within each half. Last-read: A-h0:P1 B-h0:P1 B-h1:P2
// A-h1:P3. Stages: P2 A-h0(T+2), P3 B-h0(T+2), P4 B-h1+A-h1(T+2).
// vmcnt(8) once per tile at P4 (16 outstanding -> retires all of T+1).
// Structure: 4 kernels — preprocess (x->bf16, Wt=bf16(W^T), rowsum=0),
// QKV GEMM (Q|K -> qkvb, V -> vt via epilogue transpose), scores GEMM
// (E=exp(scale*QK^T) bf16 + fp32 rowsum atomics), PV GEMM (out=(E@V)/rowsum).
// ws: xb 25.2M | Wt 3.5M | qkvb(QK) 50.3M | vt 25.2M | probs(E) 67.1M | rowsum 64K

#define NB 8
#define NS 2048
#define ND 768
#define NQK 1536   // qkvb row width (Q|K only)
#define MTOT 16384 // NB*NS

using f32x4 = __attribute__((ext_vector_type(4))) float;
using s16x8 = __attribute__((ext_vector_type(8))) short;

struct alignas(16) bf16x8 { __hip_bfloat16 h[8]; };
struct alignas(8)  bf16x4 { __hip_bfloat16 h[4]; };

// ---------------- preprocess: convert x, transpose W, zero rowsum ----------------
#define CVT_BLOCKS 4096
#define WT_BLOCKS 1728
__global__ __launch_bounds__(256) void preprocess_kernel(const float* __restrict__ x,
                                                         __hip_bfloat16* __restrict__ xb,
                                                         const float* __restrict__ W,
                                                         __hip_bfloat16* __restrict__ Wt,
                                                         float* __restrict__ rowsum) {
    __shared__ float tile[32][33];
    const int tid = threadIdx.x;
    if (blockIdx.x < CVT_BLOCKS) {
#pragma unroll
        for (int it = 0; it < 3; ++it) {
            const int i = (it * CVT_BLOCKS + blockIdx.x) * 256 + tid;
            const f32x4 v = __builtin_nontemporal_load((const f32x4*)x + i);
            bf16x4 o;
            o.h[0] = __float2bfloat16(v[0]);
            o.h[1] = __float2bfloat16(v[1]);
            o.h[2] = __float2bfloat16(v[2]);
            o.h[3] = __float2bfloat16(v[3]);
            ((bf16x4*)xb)[i] = o;
        }
    } else if (blockIdx.x < CVT_BLOCKS + WT_BLOCKS) {
        const int bid = blockIdx.x - CVT_BLOCKS;       // 0..1727 = 3*24*24
        const int e = bid / 576, rem = bid % 576;
        const int k0 = (rem / 24) * 32, n0 = (rem % 24) * 32;
        const float* Wp = W + (size_t)e * ND * ND;
        __hip_bfloat16* Wo = Wt + (size_t)e * ND * ND;
        {   // load 32x32 via float4: ty=row (32), tx=float4-col (8)
            const int ty = tid >> 3, tx = tid & 7;
            const f32x4 v = __builtin_nontemporal_load(
                (const f32x4*)&Wp[(k0 + ty) * ND + n0 + tx * 4]);
#pragma unroll
            for (int q = 0; q < 4; ++q) tile[ty][tx * 4 + q] = v[q];
        }
        __syncthreads();
        {   // store transposed: np=out row (32), kq=k-quad (8)
            const int np = tid >> 3, kq = tid & 7;
            bf16x4 o;
#pragma unroll
            for (int q = 0; q < 4; ++q) o.h[q] = __float2bfloat16(tile[kq * 4 + q][np]);
            *(bf16x4*)&Wo[(long)(n0 + np) * ND + k0 + kq * 4] = o;
        }
    } else {
        const int i = (blockIdx.x - CVT_BLOCKS - WT_BLOCKS) * 1024 + tid * 4;
        f32x4 z = {0.f, 0.f, 0.f, 0.f};
        *(f32x4*)(rowsum + i) = z;
    }
}

// ---------------- 256x256 8-phase MFMA GEMM: C = epilogue( A @ B^T ) ----------------
__device__ __forceinline__ void storeC(float* p, float v) { *p = v; }
__device__ __forceinline__ void storeC(__hip_bfloat16* p, float v) { *p = __float2bfloat16(v); }

typedef const __attribute__((address_space(1))) void* gp;
typedef __attribute__((address_space(3))) void* sp;

// Fence discipline (m201 form; NO "memory" clobbers in the hot loop):
#define BAR()      __builtin_amdgcn_s_barrier()
#define SCHED0()   __builtin_amdgcn_sched_barrier(0)
#define WAIT_LGKM0() asm volatile("s_waitcnt lgkmcnt(0)")
#define WAIT_LGKM8() asm volatile("s_waitcnt lgkmcnt(8)")
#define WAIT_VM8()   asm volatile("s_waitcnt vmcnt(8)")
#define WAIT_VM0()   asm volatile("s_waitcnt vmcnt(0)")

// Stage one 128-row half-tile (h) of A/B for K-tile T into buffer (T&1).
// 512 threads x 16B x 2 issues = 16 KiB. Global source column is pre-swizzled
// (chunk ^ (row&7)); LDS dest is linear (global_load_lds requirement, m104).
#define STAGE_AH(H_, T_) do {                                                              \
    char* d_ = smem + (((T_) & 1) * 65536) + (H_) * 16384 + ldsOff;                        \
    __builtin_amdgcn_global_load_lds((gp)(gA + (long)((H_) * 128) * lda + (T_) * 64),      \
                                     (sp)d_, 16, 0, 0);                                    \
    __builtin_amdgcn_global_load_lds((gp)(gA + (long)((H_) * 128 + 64) * lda + (T_) * 64), \
                                     (sp)(d_ + 8192), 16, 0, 0);                           \
} while (0)

#define STAGE_BH(H_, T_) do {                                                              \
    char* d_ = smem + (((T_) & 1) * 65536) + 32768 + (H_) * 16384 + ldsOff;                \
    __builtin_amdgcn_global_load_lds((gp)(gB + (long)((H_) * 128) * ldb + (T_) * 64),      \
                                     (sp)d_, 16, 0, 0);                                    \
    __builtin_amdgcn_global_load_lds((gp)(gB + (long)((H_) * 128 + 64) * ldb + (T_) * 64), \
                                     (sp)(d_ + 8192), 16, 0, 0);                           \
} while (0)

// One C-quadrant x K=64: 4 M-frags x 2 N-frags x 2 k-halves = 16 MFMAs.
#define MFMA_Q(MI0_, NI0_) do {                                                            \
    _Pragma("unroll") for (int m_ = 0; m_ < 4; ++m_)                                       \
    _Pragma("unroll") for (int n_ = 0; n_ < 2; ++n_)                                       \
    _Pragma("unroll") for (int k_ = 0; k_ < 2; ++k_)                                       \
        acc[(MI0_) + m_][(NI0_) + n_] = __builtin_amdgcn_mfma_f32_16x16x32_bf16(           \
            af[m_][k_], bf[(NI0_) + n_][k_], acc[(MI0_) + m_][(NI0_) + n_], 0, 0, 0);      \
} while (0)

// One K-tile = 4 phases, split-half mapping. SP_: enable T+2 stages.
// VM_: 0 = steady vmcnt(8), 1 = drain vmcnt(0), 2 = none.
#define KTILE(T_, SP_, VM_) do {                                                           \
    char* abase = smem + (((T_) & 1) * 65536);                                             \
    char* bbase = abase + 32768;                                                           \
    /* ---- P1: read af<-A-h0 (8), bf[0..1]<-B-h0 (4); no stage ---- */                    \
    _Pragma("unroll") for (int m_ = 0; m_ < 4; ++m_) {                                     \
        af[m_][0] = *(const s16x8*)(abase + aoff + m_ * 2048 + ck0);                       \
        af[m_][1] = *(const s16x8*)(abase + aoff + m_ * 2048 + ck1);                       \
    }                                                                                      \
    _Pragma("unroll") for (int n_ = 0; n_ < 2; ++n_) {                                     \
        bf[n_][0] = *(const s16x8*)(bbase + boff + n_ * 2048 + ck0);                       \
        bf[n_][1] = *(const s16x8*)(bbase + boff + n_ * 2048 + ck1);                       \
    }                                                                                      \
    WAIT_LGKM8();                                                                          \
    SCHED0();                                                                              \
    BAR();                                                                                 \
    WAIT_LGKM0();                                                                          \
    SCHED0();                                                                              \
    __builtin_amdgcn_s_setprio(1);                                                         \
    MFMA_Q(0, 0);                                                                          \
    __builtin_amdgcn_s_setprio(0);                                                         \
    SCHED0();                                                                              \
    BAR();                                                                                 \
    /* ---- P2: read bf[2..3]<-B-h1 (4); stage A-h0(T+2) (last read P1) ---- */            \
    _Pragma("unroll") for (int n_ = 0; n_ < 2; ++n_) {                                     \
        bf[2 + n_][0] = *(const s16x8*)(bbase + 16384 + boff + n_ * 2048 + ck0);           \
        bf[2 + n_][1] = *(const s16x8*)(bbase + 16384 + boff + n_ * 2048 + ck1);           \
    }                                                                                      \
    if (SP_) STAGE_AH(0, (T_) + 2);                                                        \
    SCHED0();                                                                              \
    BAR();                                                                                 \
    WAIT_LGKM0();                                                                          \
    SCHED0();                                                                              \
    __builtin_amdgcn_s_setprio(1);                                                         \
    MFMA_Q(0, 2);                                                                          \
    __builtin_amdgcn_s_setprio(0);                                                         \
    SCHED0();                                                                              \
    BAR();                                                                                 \
    /* ---- P3: read af<-A-h1 (8); stage B-h0(T+2) (last read P1) ---- */                  \
    _Pragma("unroll") for (int m_ = 0; m_ < 4; ++m_) {                                     \
        af[m_][0] = *(const s16x8*)(abase + 16384 + aoff + m_ * 2048 + ck0);               \
        af[m_][1] = *(const s16x8*)(abase + 16384 + aoff + m_ * 2048 + ck1);               \
    }                                                                                      \
    if (SP_) STAGE_BH(0, (T_) + 2);                                                       \
    SCHED0();                                                                              \
    BAR();                                                                                 \
    WAIT_LGKM0();                                                                          \
    SCHED0();                                                                              \
    __builtin_amdgcn_s_setprio(1);                                                         \
    MFMA_Q(4, 2);                                                                          \
    __builtin_amdgcn_s_setprio(0);                                                         \
    SCHED0();                                                                              \
    BAR();                                                                                 \
    /* ---- P4: no reads; stage B-h1(T+2)+A-h1(T+2) (last reads P2/P3); vmcnt ---- */      \
    if (SP_) { STAGE_BH(1, (T_) + 2); STAGE_AH(1, (T_) + 2); }                             \
    SCHED0();                                                                              \
    if ((VM_) == 0) { WAIT_VM8(); }                                                        \
    else if ((VM_) == 1) { WAIT_VM0(); }                                                   \
    SCHED0();                                                                              \
    BAR();                                                                                 \
    __builtin_amdgcn_s_setprio(1);                                                         \
    MFMA_Q(4, 0);                                                                          \
    __builtin_amdgcn_s_setprio(0);                                                         \
    SCHED0();                                                                              \
    BAR();                                                                                 \
} while (0)

template <typename OutT, int EPI, int NKT, bool BATCH_X>
__global__ __launch_bounds__(512, 2) void gemm256_kernel(
    const __hip_bfloat16* __restrict__ A,   // [M][lda], k-contiguous
    const __hip_bfloat16* __restrict__ Bm,  // [N][ldb], k-contiguous
    OutT* __restrict__ C,                   // [M][ldc]
    __hip_bfloat16* __restrict__ vtOut,     // EPI==2
    float* __restrict__ rowsum,             // EPI==3 (accumulate) / EPI==4 (read)
    int lda, int ldb, int ldc,
    long sA, long sB, long sC, float scale) {
    static_assert(NKT >= 4, "pipeline needs >= 4 K-tiles");
    __shared__ alignas(16) char smem[131072];  // 2 x (A 32K + B 32K)

    int b, tileM, tileN;
    if (BATCH_X) {  // batch on x => batch == linear%8 == XCD id (L2 locality)
        b = blockIdx.x; tileN = blockIdx.y * 256; tileM = blockIdx.z * 256;
    } else {        // single batch: bijective XCD swizzle (nwg % 8 == 0)
        b = 0;
        const int l0 = blockIdx.y * gridDim.x + blockIdx.x;
        const int cpx = (gridDim.x * gridDim.y) >> 3;
        const int tl = (l0 & 7) * cpx + (l0 >> 3);
        tileN = (tl % gridDim.x) * 256;
        tileM = (tl / gridDim.x) * 256;
    }
    A  += (long)b * sA;
    Bm += (long)b * sB;
    C  += (long)b * sC;

    const int tid  = threadIdx.x;
    const int lane = tid & 63;
    const int wid  = tid >> 6;   // 0..7
    const int wr   = wid >> 2;   // 0..1 : rows wr*64 within EACH 128-row half
    const int wc   = wid & 3;    // 0..3 : cols wc*32 within EACH 128-col half
    const int quad = lane >> 4;
    const int lrow = lane & 15;

    // staging: thread covers 16B; row = tid>>3 (0..63 per issue), swizzled col
    const int srow = tid >> 3;
    const int scol = ((tid & 7) ^ (srow & 7)) << 3;
    const __hip_bfloat16* gA = A + (long)(tileM + srow) * lda + scol;
    const __hip_bfloat16* gB = Bm + (long)(tileN + srow) * ldb + scol;
    const int ldsOff = tid * 16;

    // fragment-read addressing (rows are 128B; chunk XOR-swizzled by row&7)
    const int swa  = lrow & 7;
    const int ck0  = (quad ^ swa) << 4;          // kk=0 chunk byte offset
    const int ck1  = ((quad + 4) ^ swa) << 4;    // kk=1
    const int aoff = wr * 8192 + lrow * 128;     // rows wr*64.. within half
    const int boff = wc * 4096 + lrow * 128;     // cols wc*32.. within half

    f32x4 acc[8][4];
    const f32x4 zero = {0.f, 0.f, 0.f, 0.f};
#pragma unroll
    for (int i = 0; i < 8; ++i)
#pragma unroll
        for (int j = 0; j < 4; ++j) acc[i][j] = zero;

    // ---- prologue: stage tiles 0 and 1 fully; retire tile 0 (vmcnt(8)) ----
    STAGE_AH(0, 0); STAGE_BH(0, 0); STAGE_BH(1, 0); STAGE_AH(1, 0);
    STAGE_AH(0, 1); STAGE_BH(0, 1); STAGE_BH(1, 1); STAGE_AH(1, 1);
    SCHED0();
    WAIT_VM8();  // K-tile 0 complete; tile 1's 8 loads stay in flight
    SCHED0();
    BAR();

    s16x8 af[4][2], bf[4][2];
#pragma unroll 1
    for (int t = 0; t <= NKT - 3; ++t) { KTILE(t, 1, 0); }
    KTILE(NKT - 2, 0, 1);  // no stages; drain remaining (tile NKT-1) loads
    KTILE(NKT - 1, 0, 2);

    // ---------------- epilogues ----------------
    // split-half coords: row(mi,r) = tileM + (mi>>2)*128 + wr*64 + (mi&3)*16 + quad*4 + r
    //                    col(ni)   = tileN + (ni>>1)*128 + wc*32 + (ni&1)*16 + lrow
    if (EPI == 2 && tileN >= NQK) {
        // V tile: transpose 256x256 through LDS (chunk XOR d&31), store vt[b'][d][s].
        char* T = smem;
#pragma unroll
        for (int mi = 0; mi < 8; ++mi) {
#pragma unroll
            for (int ni = 0; ni < 4; ++ni) {
                const int d = ((ni >> 1) << 7) + wc * 32 + ((ni & 1) << 4) + lrow;
                const int s = ((mi >> 2) << 7) + wr * 64 + ((mi & 3) << 4) + quad * 4;
                bf16x4 g;
#pragma unroll
                for (int r = 0; r < 4; ++r) g.h[r] = __float2bfloat16(acc[mi][ni][r]);
                const int off = d * 512 + ((((s >> 3) ^ (d & 31)) << 4) | ((s & 4) << 1));
                *(bf16x4*)(T + off) = g;
            }
        }
        __syncthreads();
        const int dl = tid >> 1, half = tid & 1;
        const long bb = tileM >> 11;
        const int s0 = tileM & (NS - 1);
        const long dg = (long)(tileN - NQK) + dl;
        __hip_bfloat16* dst = vtOut + (bb * ND + dg) * NS + s0;
#pragma unroll
        for (int cc = 0; cc < 16; ++cc) {
            const int c2 = half * 16 + cc;
            s16x8 val = *(const s16x8*)(T + dl * 512 + ((c2 ^ (dl & 31)) << 4));
            *(s16x8*)(dst + c2 * 8) = val;
        }
        return;
    }

    if (EPI == 3) {
        // scores: store unnormalized E = exp(scale*acc) bf16; row-sum atomics.
        // Sum uses the bf16-ROUNDED values so normalization matches PV's input.
#pragma unroll
        for (int mi = 0; mi < 8; ++mi) {
            const int rowb = tileM + ((mi >> 2) << 7) + wr * 64 + ((mi & 3) << 4) + quad * 4;
            float rs[4] = {0.f, 0.f, 0.f, 0.f};
#pragma unroll
            for (int ni = 0; ni < 4; ++ni) {
                const int col = tileN + ((ni >> 1) << 7) + wc * 32 + ((ni & 1) << 4) + lrow;
#pragma unroll
                for (int r = 0; r < 4; ++r) {
                    const float e = __expf(acc[mi][ni][r] * scale);  // |logit|<~2.5: safe
                    const __hip_bfloat16 h = __float2bfloat16(e);
                    storeC(C + (long)(rowb + r) * ldc + col, __bfloat162float(h));
                    rs[r] += __bfloat162float(h);
                }
            }
#pragma unroll
            for (int r = 0; r < 4; ++r) {
#pragma unroll
                for (int off = 1; off < 16; off <<= 1) rs[r] += __shfl_xor(rs[r], off);
            }
            if (lrow == 0) {
#pragma unroll
                for (int r = 0; r < 4; ++r)
                    atomicAdd(rowsum + (long)b * NS + rowb + r, rs[r]);
            }
        }
        return;
    }

    if (EPI == 4) {
        // PV: normalize by row sum.
#pragma unroll
        for (int mi = 0; mi < 8; ++mi) {
            const int rowb = tileM + ((mi >> 2) << 7) + wr * 64 + ((mi & 3) << 4) + quad * 4;
            float inv[4];
#pragma unroll
            for (int r = 0; r < 4; ++r)
                inv[r] = 1.0f / rowsum[(long)b * NS + rowb + r];
#pragma unroll
            for (int ni = 0; ni < 4; ++ni) {
                const int col = tileN + ((ni >> 1) << 7) + wc * 32 + ((ni & 1) << 4) + lrow;
#pragma unroll
                for (int r = 0; r < 4; ++r)
                    storeC(C + (long)(rowb + r) * ldc + col, acc[mi][ni][r] * inv[r]);
            }
        }
        return;
    }

    // EPI==2 Q|K path: plain bf16 store
#pragma unroll
    for (int mi = 0; mi < 8; ++mi) {
        const int rowb = tileM + ((mi >> 2) << 7) + wr * 64 + ((mi & 3) << 4) + quad * 4;
#pragma unroll
        for (int ni = 0; ni < 4; ++ni) {
            const int col = tileN + ((ni >> 1) << 7) + wc * 32 + ((ni & 1) << 4) + lrow;
#pragma unroll
            for (int r = 0; r < 4; ++r)
                storeC(C + (long)(rowb + r) * ldc + col, acc[mi][ni][r] * scale);
        }
    }
}

// ---------------- launch ----------------
extern "C" void kernel_launch(void* const* d_in, const int* in_sizes, int n_in,
                              void* d_out, int out_size, void* d_ws, size_t ws_size,
                              hipStream_t stream) {
    const float* x   = (const float*)d_in[0];  // [8][2048][768]
    const float* QKV = (const float*)d_in[1];  // [3][768][768]
    float* out = (float*)d_out;                // [8][2048][768]

    uint8_t* ws = (uint8_t*)d_ws;
    constexpr size_t XB_BYTES  = (size_t)MTOT * ND * 2;     // 25.2M
    constexpr size_t WT_BYTES  = (size_t)3 * ND * ND * 2;   //  3.5M
    constexpr size_t QKV_BYTES = (size_t)MTOT * NQK * 2;    // 50.3M (Q|K only)
    constexpr size_t VT_BYTES  = (size_t)NB * ND * NS * 2;  // 25.2M
    constexpr size_t PR_BYTES  = (size_t)MTOT * NS * 2;     // 67.1M
    __hip_bfloat16* xb    = (__hip_bfloat16*)(ws);
    __hip_bfloat16* Wt    = (__hip_bfloat16*)(ws + XB_BYTES);
    __hip_bfloat16* qkvb  = (__hip_bfloat16*)(ws + XB_BYTES + WT_BYTES);
    __hip_bfloat16* vt    = (__hip_bfloat16*)(ws + XB_BYTES + WT_BYTES + QKV_BYTES);
    __hip_bfloat16* probs = (__hip_bfloat16*)(ws + XB_BYTES + WT_BYTES + QKV_BYTES + VT_BYTES);
    float*          rowsum= (float*)(ws + XB_BYTES + WT_BYTES + QKV_BYTES + VT_BYTES + PR_BYTES);

    const float scale = 0.03608439182435161f;  // 1/sqrt(768)

    // 1. preprocess: xb = bf16(x); Wt = bf16(W^T); rowsum = 0
    preprocess_kernel<<<CVT_BLOCKS + WT_BLOCKS + 16, 256, 0, stream>>>(x, xb, QKV, Wt, rowsum);
    // 2. fused QKV projection: Q|K -> qkvb [16384][1536]; V -> vt[b][d][s]
    //    grid 9x64 = 576 tiles (256x256), K=768 (NKT=12)
    gemm256_kernel<__hip_bfloat16, 2, 12, false><<<dim3(2304 / 256, MTOT / 256, 1), 512, 0, stream>>>(
        xb, Wt, qkvb, vt, nullptr, ND, ND, NQK, 0, 0, 0, 1.0f);
    // 3. E = exp(scale * Q K^T), rowsum += (batch on x for XCD-L2 locality)
    gemm256_kernel<__hip_bfloat16, 3, 12, true><<<dim3(NB, NS / 256, NS / 256), 512, 0, stream>>>(
        qkvb, qkvb + ND, probs, nullptr, rowsum, NQK, NQK, NS,
        (long)NS * NQK, (long)NS * NQK, (long)NS * NS, scale);
    // 4. out = (E @ V) / rowsum  (fp32 out), K=2048 (NKT=32)
    gemm256_kernel<float, 4, 32, true><<<dim3(NB, ND / 256, NS / 256), 512, 0, stream>>>(
        probs, vt, out, nullptr, rowsum, NS, NS, ND,
        (long)NS * NS, (long)ND * NS, (long)NS * ND, 1.0f);
}

// Round 5
// 286.570 us; speedup vs baseline: 1.0782x; 1.0782x over previous
//
#include <hip/hip_runtime.h>
#include <hip/hip_bf16.h>
#include <cstdint>

// SelfAttention: B=8, S=2048, D_IN=D_OUT=768, fp32 in/out.
// R13 = R8 revert + bijective XCD swizzle on the QKV GEMM grid.
// R9-R12 post-mortem: 256x256 8-phase port (4 variants: contiguous map,
// split-half map, memory-clobber fences, clean fences+sched_barrier) all
// landed at 83us/GEMM, MfmaUtil 27% — identical across variants => not a
// schedule bug. Arithmetic: 24 ds_read_b128/wave/K-tile x 8 waves = 192KB
// LDS traffic vs 620 cyc MFMA per CU per tile => LDS-read-bound cap ~36%
// MfmaUtil. The 8-phase geometry is structurally worse here than R8's
// 128^2 3-blocks/CU form. Reverted.
// R8 structure: 4 kernels — preprocess (x->bf16, Wt=bf16(W^T), rowsum=0),
// QKV GEMM (Q|K -> qkvb, V -> vt via epilogue transpose), scores GEMM
// (E=exp(scale*QK^T) bf16 + fp32 rowsum atomics), PV GEMM (out=(E@V)/rowsum).
// GEMM core: 128x128 tile, BK=64, XOR-swizzled LDS (0 bank conflicts),
// global_load_lds width=16; ~30% MfmaUtil = m97 plateau (not movable from
// HIP source, m99-m141; 8-phase falsified here R10-R12).
// R13 delta: QKV grid was N-fastest => the 18 blocks sharing an A-panel
// spread over all 8 XCDs (each XCD streams ~25MB xb via its L2). Chunked
// bijective swizzle (nwg=2304 % 8 == 0) gives each XCD 16 contiguous
// M-tiles (~3MB A per XCD). scores/PV already batch-on-x = XCD-aligned.
// ws: xb 25.2M | Wt 3.5M | qkvb(QK) 50.3M | vt 25.2M | probs(E) 67.1M | rowsum 64K

#define NB 8
#define NS 2048
#define ND 768
#define NQK 1536   // qkvb row width (Q|K only)
#define MTOT 16384 // NB*NS

using f32x4 = __attribute__((ext_vector_type(4))) float;
using s16x8 = __attribute__((ext_vector_type(8))) short;

struct alignas(16) bf16x8 { __hip_bfloat16 h[8]; };
struct alignas(8)  bf16x4 { __hip_bfloat16 h[4]; };

// ---------------- preprocess: convert x, transpose W, zero rowsum ----------------
// blocks [0, 4096): xb = bf16(x), 3 float4/thread (4096*256*3 = 3,145,728 = MTOT*ND/4)
// blocks [4096, 4096+1728): Wt[e][n][k] = bf16(W[e][k][n]), 32x32 tiles
// blocks [5824, 5840): rowsum = 0
#define CVT_BLOCKS 4096
#define WT_BLOCKS 1728
__global__ __launch_bounds__(256) void preprocess_kernel(const float* __restrict__ x,
                                                         __hip_bfloat16* __restrict__ xb,
                                                         const float* __restrict__ W,
                                                         __hip_bfloat16* __restrict__ Wt,
                                                         float* __restrict__ rowsum) {
    __shared__ float tile[32][33];
    const int tid = threadIdx.x;
    if (blockIdx.x < CVT_BLOCKS) {
#pragma unroll
        for (int it = 0; it < 3; ++it) {
            const int i = (it * CVT_BLOCKS + blockIdx.x) * 256 + tid;
            const f32x4 v = __builtin_nontemporal_load((const f32x4*)x + i);
            bf16x4 o;
            o.h[0] = __float2bfloat16(v[0]);
            o.h[1] = __float2bfloat16(v[1]);
            o.h[2] = __float2bfloat16(v[2]);
            o.h[3] = __float2bfloat16(v[3]);
            ((bf16x4*)xb)[i] = o;
        }
    } else if (blockIdx.x < CVT_BLOCKS + WT_BLOCKS) {
        const int bid = blockIdx.x - CVT_BLOCKS;       // 0..1727 = 3*24*24
        const int e = bid / 576, rem = bid % 576;
        const int k0 = (rem / 24) * 32, n0 = (rem % 24) * 32;
        const float* Wp = W + (size_t)e * ND * ND;
        __hip_bfloat16* Wo = Wt + (size_t)e * ND * ND;
        {   // load 32x32 via float4: ty=row (32), tx=float4-col (8)
            const int ty = tid >> 3, tx = tid & 7;
            const f32x4 v = __builtin_nontemporal_load(
                (const f32x4*)&Wp[(k0 + ty) * ND + n0 + tx * 4]);
#pragma unroll
            for (int q = 0; q < 4; ++q) tile[ty][tx * 4 + q] = v[q];
        }
        __syncthreads();
        {   // store transposed: np=out row (32), kq=k-quad (8)
            const int np = tid >> 3, kq = tid & 7;
            bf16x4 o;
#pragma unroll
            for (int q = 0; q < 4; ++q) o.h[q] = __float2bfloat16(tile[kq * 4 + q][np]);
            *(bf16x4*)&Wo[(long)(n0 + np) * ND + k0 + kq * 4] = o;
        }
    } else {
        const int i = (blockIdx.x - CVT_BLOCKS - WT_BLOCKS) * 1024 + tid * 4;
        f32x4 z = {0.f, 0.f, 0.f, 0.f};
        *(f32x4*)(rowsum + i) = z;
    }
}

// ---------------- MFMA GEMM: C[m][n] = epilogue( sum_k A[m][k]*B[n][k] ) ----------------
// 128x128 tile, BK=64, 4 waves, 4x4 16x16x32 MFMAs/wave, global_load_lds
// width=16 staging, XOR-swizzled LDS (0 bank conflicts, measured R2/R3).
// EPI 2: QKV split (tileN<1536 -> bf16 C; else transpose tile -> vt[b][d][s])
// EPI 3: scores    (store bf16 exp(scale*acc), atomicAdd fp32 row sums)
// EPI 4: PV        (f32 C scaled by 1/rowsum[row])
__device__ __forceinline__ void storeC(float* p, float v) { *p = v; }
__device__ __forceinline__ void storeC(__hip_bfloat16* p, float v) { *p = __float2bfloat16(v); }

template <typename OutT, int EPI, bool BATCH_X>
__global__ __launch_bounds__(256, 3) void gemm_bt_kernel(
    const __hip_bfloat16* __restrict__ A,   // [M][lda], k-contiguous
    const __hip_bfloat16* __restrict__ Bm,  // [N][ldb], k-contiguous
    OutT* __restrict__ C,                   // [M][ldc]
    __hip_bfloat16* __restrict__ vtOut,     // EPI==2
    float* __restrict__ rowsum,             // EPI==3 (accumulate) / EPI==4 (read)
    int K, int lda, int ldb, int ldc,
    long sA, long sB, long sC, float scale) {
    __shared__ char smem[32768];
    char* AsB = smem;
    char* BsB = smem + 16384;

    int b, tileM, tileN;
    if (BATCH_X) {  // batch on x => batch == linear%8 == XCD id (L2 locality)
        b = blockIdx.x; tileN = blockIdx.y * 128; tileM = blockIdx.z * 128;
    } else {        // single batch: bijective chunked XCD swizzle (nwg % 8 == 0)
        b = 0;
        const int nwg = gridDim.x * gridDim.y;              // 18*128 = 2304
        const int l0  = blockIdx.y * gridDim.x + blockIdx.x;
        const int q   = nwg >> 3;                           // 288
        const int swz = (l0 & 7) * q + (l0 >> 3);           // XCD-chunked
        tileN = (swz % gridDim.x) * 128;
        tileM = (swz / gridDim.x) * 128;
    }
    A  += (long)b * sA;
    Bm += (long)b * sB;
    C  += (long)b * sC;

    const int tid  = threadIdx.x;
    const int lane = tid & 63;
    const int wave = tid >> 6;
    const int wm = (wave >> 1) * 64;
    const int wn = (wave & 1) * 64;
    const int quad = lane >> 4;
    const int lrow = lane & 15;

    // staging: thread covers 16B; row = tid>>3 (0..31), swizzled col chunk
    const int srow = tid >> 3;
    const int scol = ((tid & 7) ^ (srow & 7)) << 3;

    f32x4 acc[4][4];
    const f32x4 zero = {0.f, 0.f, 0.f, 0.f};
#pragma unroll
    for (int i = 0; i < 4; ++i)
#pragma unroll
        for (int j = 0; j < 4; ++j) acc[i][j] = zero;

    const __hip_bfloat16* gA = A + (long)(tileM + srow) * lda + scol;
    const __hip_bfloat16* gB = Bm + (long)(tileN + srow) * ldb + scol;
    const int ldsOff = tid * 16;  // bytes; dest = wave-uniform base + lane*16

    typedef const __attribute__((address_space(1))) void* gp;
    typedef __attribute__((address_space(3))) void* sp;

    const int swa = (lrow & 7) << 4;  // XOR byte swizzle for fragment reads

    for (int k0 = 0; k0 < K; k0 += 64) {
        __syncthreads();
#pragma unroll
        for (int j = 0; j < 4; ++j)
            __builtin_amdgcn_global_load_lds((gp)(gA + (long)(j * 32) * lda + k0),
                                             (sp)(AsB + j * 4096 + ldsOff), 16, 0, 0);
#pragma unroll
        for (int j = 0; j < 4; ++j)
            __builtin_amdgcn_global_load_lds((gp)(gB + (long)(j * 32) * ldb + k0),
                                             (sp)(BsB + j * 4096 + ldsOff), 16, 0, 0);
        __syncthreads();

#pragma unroll
        for (int kk = 0; kk < 2; ++kk) {
            s16x8 af[4], bfr[4];
#pragma unroll
            for (int i = 0; i < 4; ++i)
                af[i] = *(const s16x8*)(AsB + (wm + i * 16 + lrow) * 128 +
                                        ((((kk << 2) | quad) << 4) ^ swa));
#pragma unroll
            for (int j = 0; j < 4; ++j)
                bfr[j] = *(const s16x8*)(BsB + (wn + j * 16 + lrow) * 128 +
                                         ((((kk << 2) | quad) << 4) ^ swa));
#pragma unroll
            for (int i = 0; i < 4; ++i)
#pragma unroll
                for (int j = 0; j < 4; ++j)
                    acc[i][j] = __builtin_amdgcn_mfma_f32_16x16x32_bf16(af[i], bfr[j], acc[i][j], 0, 0, 0);
        }
    }

    // ---------------- epilogues ----------------
    if (EPI == 2 && tileN >= NQK) {
        // V tile: transpose through LDS, store to vt[b'][d][s].
        __syncthreads();
        char* T = smem;  // 32KB scratch
#pragma unroll
        for (int i = 0; i < 4; ++i) {
#pragma unroll
            for (int j = 0; j < 4; ++j) {
                const int d = wn + j * 16 + lrow;       // local col (V feature)
                const int s = wm + i * 16 + quad * 4;   // granule of 4 rows
                bf16x4 g;
#pragma unroll
                for (int r = 0; r < 4; ++r) g.h[r] = __float2bfloat16(acc[i][j][r]);
                const int c = s >> 3;
                const int off = d * 256 + (((c ^ (d & 15)) << 4) | ((s & 4) << 1));
                *(bf16x4*)(T + off) = g;
            }
        }
        __syncthreads();
        const int dl = tid >> 1, half = tid & 1;
        const long bb = tileM >> 11;
        const int s0 = tileM & (NS - 1);
        const long dg = (long)(tileN - NQK) + dl;
        __hip_bfloat16* dst = vtOut + (bb * ND + dg) * NS + s0;
#pragma unroll
        for (int cc = 0; cc < 8; ++cc) {
            const int c2 = half * 8 + cc;
            s16x8 val = *(const s16x8*)(T + dl * 256 + ((c2 ^ (dl & 15)) << 4));
            *(s16x8*)(dst + c2 * 8) = val;
        }
        return;
    }

    if (EPI == 3) {
        // scores: store unnormalized E = exp(scale*acc) bf16; row-sum atomics.
        // Sum uses the bf16-ROUNDED values so normalization matches PV's input.
#pragma unroll
        for (int i = 0; i < 4; ++i) {
            float rs[4] = {0.f, 0.f, 0.f, 0.f};
#pragma unroll
            for (int j = 0; j < 4; ++j) {
                const int col = tileN + wn + j * 16 + lrow;
#pragma unroll
                for (int r = 0; r < 4; ++r) {
                    const int row = tileM + wm + i * 16 + quad * 4 + r;
                    const float e = __expf(acc[i][j][r] * scale);  // |logit|<~2.5: safe
                    const __hip_bfloat16 h = __float2bfloat16(e);
                    storeC(C + (long)row * ldc + col, __bfloat162float(h));
                    rs[r] += __bfloat162float(h);
                }
            }
#pragma unroll
            for (int r = 0; r < 4; ++r) {
#pragma unroll
                for (int off = 1; off < 16; off <<= 1) rs[r] += __shfl_xor(rs[r], off);
            }
            if (lrow == 0) {
#pragma unroll
                for (int r = 0; r < 4; ++r)
                    atomicAdd(rowsum + (long)b * NS + tileM + wm + i * 16 + quad * 4 + r, rs[r]);
            }
        }
        return;
    }

    if (EPI == 4) {
        // PV: normalize by row sum.
#pragma unroll
        for (int i = 0; i < 4; ++i) {
            float inv[4];
#pragma unroll
            for (int r = 0; r < 4; ++r)
                inv[r] = 1.0f / rowsum[(long)b * NS + tileM + wm + i * 16 + quad * 4 + r];
#pragma unroll
            for (int j = 0; j < 4; ++j) {
                const int col = tileN + wn + j * 16 + lrow;
#pragma unroll
                for (int r = 0; r < 4; ++r) {
                    const int row = tileM + wm + i * 16 + quad * 4 + r;
                    storeC(C + (long)row * ldc + col, acc[i][j][r] * inv[r]);
                }
            }
        }
        return;
    }

    // EPI==2 Q|K path: plain bf16 store
#pragma unroll
    for (int i = 0; i < 4; ++i) {
#pragma unroll
        for (int j = 0; j < 4; ++j) {
            const int col = tileN + wn + j * 16 + lrow;
#pragma unroll
            for (int r = 0; r < 4; ++r) {
                const int row = tileM + wm + i * 16 + quad * 4 + r;
                storeC(C + (long)row * ldc + col, acc[i][j][r] * scale);
            }
        }
    }
}

// ---------------- launch ----------------
extern "C" void kernel_launch(void* const* d_in, const int* in_sizes, int n_in,
                              void* d_out, int out_size, void* d_ws, size_t ws_size,
                              hipStream_t stream) {
    const float* x   = (const float*)d_in[0];  // [8][2048][768]
    const float* QKV = (const float*)d_in[1];  // [3][768][768]
    float* out = (float*)d_out;                // [8][2048][768]

    uint8_t* ws = (uint8_t*)d_ws;
    constexpr size_t XB_BYTES  = (size_t)MTOT * ND * 2;     // 25.2M
    constexpr size_t WT_BYTES  = (size_t)3 * ND * ND * 2;   //  3.5M
    constexpr size_t QKV_BYTES = (size_t)MTOT * NQK * 2;    // 50.3M (Q|K only)
    constexpr size_t VT_BYTES  = (size_t)NB * ND * NS * 2;  // 25.2M
    constexpr size_t PR_BYTES  = (size_t)MTOT * NS * 2;     // 67.1M
    __hip_bfloat16* xb    = (__hip_bfloat16*)(ws);
    __hip_bfloat16* Wt    = (__hip_bfloat16*)(ws + XB_BYTES);
    __hip_bfloat16* qkvb  = (__hip_bfloat16*)(ws + XB_BYTES + WT_BYTES);
    __hip_bfloat16* vt    = (__hip_bfloat16*)(ws + XB_BYTES + WT_BYTES + QKV_BYTES);
    __hip_bfloat16* probs = (__hip_bfloat16*)(ws + XB_BYTES + WT_BYTES + QKV_BYTES + VT_BYTES);
    float*          rowsum= (float*)(ws + XB_BYTES + WT_BYTES + QKV_BYTES + VT_BYTES + PR_BYTES);

    const float scale = 0.03608439182435161f;  // 1/sqrt(768)

    // 1. preprocess: xb = bf16(x); Wt = bf16(W^T); rowsum = 0
    preprocess_kernel<<<CVT_BLOCKS + WT_BLOCKS + 16, 256, 0, stream>>>(x, xb, QKV, Wt, rowsum);
    // 2. fused QKV projection: Q|K -> qkvb [16384][1536]; V -> vt[b][d][s]
    gemm_bt_kernel<__hip_bfloat16, 2, false><<<dim3(2304 / 128, MTOT / 128, 1), 256, 0, stream>>>(
        xb, Wt, qkvb, vt, nullptr, ND, ND, ND, NQK, 0, 0, 0, 1.0f);
    // 3. E = exp(scale * Q K^T), rowsum += (per batch; batch on x for XCD-L2 locality)
    gemm_bt_kernel<__hip_bfloat16, 3, true><<<dim3(NB, NS / 128, NS / 128), 256, 0, stream>>>(
        qkvb, qkvb + ND, probs, nullptr, rowsum, ND, NQK, NQK, NS,
        (long)NS * NQK, (long)NS * NQK, (long)NS * NS, scale);
    // 4. out = (E @ V) / rowsum  (fp32 out)
    gemm_bt_kernel<float, 4, true><<<dim3(NB, ND / 128, NS / 128), 256, 0, stream>>>(
        probs, vt, out, nullptr, rowsum, NS, NS, NS, ND,
        (long)NS * NS, (long)ND * NS, (long)NS * ND, 1.0f);
}